// Round 1
// baseline (1489.921 us; speedup 1.0000x reference)
//
#include <hip/hip_runtime.h>
#include <hip/hip_bf16.h>

#define IN_DIM 2048
#define HID    1024
#define ATT    40
#define BATCH  4096

#define BM 128
#define BN 128
#define BK 64

typedef unsigned short u16;
typedef __attribute__((ext_vector_type(8))) __bf16 bf16x8;
typedef __attribute__((ext_vector_type(4))) float  f32x4;

struct alignas(8) u16x4 { u16 x, y, z, w; };

__device__ __forceinline__ u16 f2bf(float f) {
    unsigned int u = __float_as_uint(f);
    unsigned int r = (u + 0x7fffu + ((u >> 16) & 1u)) >> 16;   // RNE
    return (u16)r;
}

// async global->LDS 16B/lane; LDS dest is wave-uniform base + lane*16
__device__ __forceinline__ void load16_to_lds(const void* g, void* l) {
    __builtin_amdgcn_global_load_lds(
        (const __attribute__((address_space(1))) unsigned int*)(uintptr_t)g,
        (__attribute__((address_space(3))) unsigned int*)(uintptr_t)l,
        16, 0, 0);
}

// ---------------- x fp32 -> bf16 (same layout) ----------------
__global__ void convert_x(const float* __restrict__ x, u16* __restrict__ xb) {
    int i = (blockIdx.x * 256 + threadIdx.x) * 4;
    float4 v = *(const float4*)(x + i);
    u16x4 o = { f2bf(v.x), f2bf(v.y), f2bf(v.z), f2bf(v.w) };
    *(u16x4*)(xb + i) = o;
}

// ---------------- W1 (a,d,h) fp32 -> (a,h,d) bf16 ----------------
__global__ void transpose_w1(const float* __restrict__ W1, u16* __restrict__ W1t) {
    __shared__ u16 tile[64][72];   // pad to soften write-phase conflicts
    const int a  = blockIdx.z;
    const int d0 = blockIdx.y * 64;
    const int h0 = blockIdx.x * 64;
    const int tr = threadIdx.x >> 4;   // 0..15
    const int tc = threadIdx.x & 15;   // 0..15
    const float* src = W1 + (size_t)a * IN_DIM * HID;
    u16* dst = W1t + (size_t)a * HID * IN_DIM;
    #pragma unroll
    for (int it = 0; it < 4; ++it) {
        int d = it * 16 + tr;
        float4 v = *(const float4*)(src + (size_t)(d0 + d) * HID + h0 + tc * 4);
        tile[d][tc * 4 + 0] = f2bf(v.x);
        tile[d][tc * 4 + 1] = f2bf(v.y);
        tile[d][tc * 4 + 2] = f2bf(v.z);
        tile[d][tc * 4 + 3] = f2bf(v.w);
    }
    __syncthreads();
    #pragma unroll
    for (int it = 0; it < 4; ++it) {
        int h = it * 16 + tr;
        u16x4 o = { tile[tc * 4 + 0][h], tile[tc * 4 + 1][h],
                    tile[tc * 4 + 2][h], tile[tc * 4 + 3][h] };
        *(u16x4*)(dst + (size_t)(h0 + h) * IN_DIM + d0 + tc * 4) = o;
    }
}

// ---------------- fused GEMM + bias + gelu + W2-dot (atomic partials) ----------------
__global__ __launch_bounds__(256) void gemm_fused(
    const u16* __restrict__ xb,    // [4096][2048] bf16
    const u16* __restrict__ w1t,   // [40][1024][2048] bf16 (B^T: n-major, k-contig)
    const float* __restrict__ b1,  // [40][1024]
    const float* __restrict__ w2,  // [40][1024]
    float* __restrict__ partial)   // [4096][40], pre-zeroed
{
    __shared__ __align__(16) u16 smem[2 * BM * BK];   // A:[0,8192) B:[8192,16384) u16
    const int a  = blockIdx.z;
    const int m0 = blockIdx.x * BM;
    const int n0 = blockIdx.y * BN;

    const int tid  = threadIdx.x;
    const int w    = tid >> 6;
    const int l    = tid & 63;
    const int quad = l >> 4;
    const int lr   = l & 15;
    const int wm   = (w >> 1) * 64;   // wave's row offset in tile
    const int wn   = (w & 1) * 64;    // wave's col offset in tile

    const u16* Abase = xb + (size_t)m0 * IN_DIM;
    const u16* Bbase = w1t + (size_t)a * ((size_t)HID * IN_DIM) + (size_t)n0 * IN_DIM;

    f32x4 acc[4][4];
    #pragma unroll
    for (int i = 0; i < 4; ++i)
        #pragma unroll
        for (int j = 0; j < 4; ++j)
            acc[i][j] = (f32x4){0.f, 0.f, 0.f, 0.f};

    for (int k0 = 0; k0 < IN_DIM; k0 += BK) {
        // ---- stage A and B tiles: 16B/lane async, XOR-swizzled k-chunks ----
        #pragma unroll
        for (int j = 0; j < 4; ++j) {
            int p   = j * 256 + w * 64 + l;        // physical 16B chunk 0..1023
            int row = p >> 3;
            int kc  = (p & 7) ^ (row & 7);         // logical k-chunk stored here
            load16_to_lds(Abase + (size_t)row * IN_DIM + k0 + kc * 8,
                          &smem[(j * 256 + w * 64) * 8]);
        }
        #pragma unroll
        for (int j = 0; j < 4; ++j) {
            int p   = j * 256 + w * 64 + l;
            int row = p >> 3;
            int kc  = (p & 7) ^ (row & 7);
            load16_to_lds(Bbase + (size_t)row * IN_DIM + k0 + kc * 8,
                          &smem[BM * BK + (j * 256 + w * 64) * 8]);
        }
        __syncthreads();   // compiler drains vmcnt before s_barrier

        // ---- compute: 2 K-steps x 4x4 fragments ----
        #pragma unroll
        for (int ks = 0; ks < 2; ++ks) {
            bf16x8 af[4], bfr[4];
            #pragma unroll
            for (int fm = 0; fm < 4; ++fm) {
                int row = wm + fm * 16 + lr;
                int kc  = (ks * 4 + quad) ^ (row & 7);
                af[fm] = *(const bf16x8*)&smem[row * BK + kc * 8];
            }
            #pragma unroll
            for (int fn = 0; fn < 4; ++fn) {
                int row = wn + fn * 16 + lr;
                int kc  = (ks * 4 + quad) ^ (row & 7);
                bfr[fn] = *(const bf16x8*)&smem[BM * BK + row * BK + kc * 8];
            }
            #pragma unroll
            for (int fm = 0; fm < 4; ++fm)
                #pragma unroll
                for (int fn = 0; fn < 4; ++fn)
                    acc[fm][fn] = __builtin_amdgcn_mfma_f32_16x16x32_bf16(
                        af[fm], bfr[fn], acc[fm][fn], 0, 0, 0);
        }
        __syncthreads();
    }

    // ---- epilogue: +b1, exact gelu, *W2, reduce over this tile's 128 cols ----
    float b1v[4], w2v[4];
    #pragma unroll
    for (int fn = 0; fn < 4; ++fn) {
        int col = n0 + wn + fn * 16 + lr;
        b1v[fn] = b1[a * HID + col];
        w2v[fn] = w2[a * HID + col];
    }
    #pragma unroll
    for (int fm = 0; fm < 4; ++fm) {
        #pragma unroll
        for (int r = 0; r < 4; ++r) {
            float s = 0.f;
            #pragma unroll
            for (int fn = 0; fn < 4; ++fn) {
                float z = acc[fm][fn][r] + b1v[fn];
                float g = 0.5f * z * (1.0f + erff(z * 0.70710678118654752f));
                s += g * w2v[fn];
            }
            // sum across the 16 lanes of this quad (cols)
            s += __shfl_xor(s, 1, 64);
            s += __shfl_xor(s, 2, 64);
            s += __shfl_xor(s, 4, 64);
            s += __shfl_xor(s, 8, 64);
            if (lr == 0) {
                int grow = m0 + wm + fm * 16 + quad * 4 + r;
                atomicAdd(&partial[grow * ATT + a], s);
            }
        }
    }
}

// ---------------- sigmoid(partial + b2) -> out ----------------
__global__ void finish_kernel(const float* __restrict__ partial,
                              const float* __restrict__ b2,
                              float* __restrict__ out, int n) {
    int i = blockIdx.x * 256 + threadIdx.x;
    if (i < n) {
        float z = partial[i] + b2[i % ATT];
        out[i] = 1.0f / (1.0f + expf(-z));
    }
}

extern "C" void kernel_launch(void* const* d_in, const int* in_sizes, int n_in,
                              void* d_out, int out_size, void* d_ws, size_t ws_size,
                              hipStream_t stream) {
    const float* x  = (const float*)d_in[0];
    const float* W1 = (const float*)d_in[1];
    const float* b1 = (const float*)d_in[2];
    const float* W2 = (const float*)d_in[3];
    const float* b2 = (const float*)d_in[4];
    float* out = (float*)d_out;

    char* ws = (char*)d_ws;
    float* partial = (float*)ws;                                   // 640 KB
    u16*   xb      = (u16*)(ws + 655360);                          // 16 MB
    u16*   w1t     = (u16*)(ws + 655360 + 16777216);               // 160 MB
    // total ws needed: 185,204,736 bytes

    hipMemsetAsync(partial, 0, (size_t)BATCH * ATT * sizeof(float), stream);
    convert_x<<<dim3(BATCH * IN_DIM / (256 * 4)), dim3(256), 0, stream>>>(x, xb);
    transpose_w1<<<dim3(HID / 64, IN_DIM / 64, ATT), dim3(256), 0, stream>>>(W1, w1t);
    gemm_fused<<<dim3(BATCH / BM, HID / BN, ATT), dim3(256), 0, stream>>>(
        xb, w1t, b1, W2, partial);
    finish_kernel<<<dim3((BATCH * ATT + 255) / 256), dim3(256), 0, stream>>>(
        partial, b2, out, BATCH * ATT);
}

// Round 2
// 1155.068 us; speedup vs baseline: 1.2899x; 1.2899x over previous
//
#include <hip/hip_runtime.h>
#include <hip/hip_bf16.h>

#define IN_DIM 2048
#define HID    1024
#define ATT    40
#define BATCH  4096

#define BM 128
#define BN 128
#define BK 64

typedef unsigned short u16;
typedef __attribute__((ext_vector_type(8))) __bf16 bf16x8;
typedef __attribute__((ext_vector_type(4))) float  f32x4;

struct alignas(8)  u16x4 { u16 a, b, c, d; };
struct alignas(16) u16x8 { u16x4 lo, hi; };

__device__ __forceinline__ u16 f2bf(float f) {
    unsigned int u = __float_as_uint(f);
    unsigned int r = (u + 0x7fffu + ((u >> 16) & 1u)) >> 16;   // RNE
    return (u16)r;
}
__device__ __forceinline__ float f4get(const float4& v, int j) {
    return reinterpret_cast<const float*>(&v)[j];
}

// async global->LDS 16B/lane; LDS dest is wave-uniform base + lane*16
__device__ __forceinline__ void load16_to_lds(const void* g, void* l) {
    __builtin_amdgcn_global_load_lds(
        (const __attribute__((address_space(1))) unsigned int*)(uintptr_t)g,
        (__attribute__((address_space(3))) unsigned int*)(uintptr_t)l,
        16, 0, 0);
}

// ---------------- x fp32 -> bf16 (same layout) ----------------
__global__ void convert_x(const float* __restrict__ x, u16* __restrict__ xb) {
    int i = (blockIdx.x * 256 + threadIdx.x) * 4;
    float4 v = *(const float4*)(x + i);
    u16x4 o = { f2bf(v.x), f2bf(v.y), f2bf(v.z), f2bf(v.w) };
    *(u16x4*)(xb + i) = o;
}

// ---------------- W1 (a,d,h) fp32 -> (a,h,d) bf16, vectorized both phases --------
// 64(d) x 64(h) tile. Phase 1: in-register 4x4 transpose, b64 writes to
// XOR-swizzled [h][d] tile (8-u16 chunk index ^ (h&15)). Phase 2: b64 reads,
// 16B/lane coalesced global stores.
__global__ void transpose_w1(const float* __restrict__ W1, u16* __restrict__ W1t) {
    __shared__ u16 tile[64 * 64];
    const int a  = blockIdx.z;
    const int d0 = blockIdx.y * 64;
    const int h0 = blockIdx.x * 64;
    const float* src = W1 + (size_t)a * IN_DIM * HID + (size_t)d0 * HID + h0;
    u16* dst = W1t + (size_t)a * HID * IN_DIM + (size_t)h0 * IN_DIM + d0;

    const int tr = threadIdx.x >> 4;   // 0..15  -> d-chunk of 4
    const int tc = threadIdx.x & 15;   // 0..15  -> h-chunk of 4
    float4 v[4];
    #pragma unroll
    for (int p = 0; p < 4; ++p)
        v[p] = *(const float4*)(src + (size_t)(tr * 4 + p) * HID + tc * 4);
    #pragma unroll
    for (int j = 0; j < 4; ++j) {
        int h = tc * 4 + j;
        int phys = tr ^ (h & 15);                 // 4-elem chunk position
        u16x4 o = { f2bf(f4get(v[0], j)), f2bf(f4get(v[1], j)),
                    f2bf(f4get(v[2], j)), f2bf(f4get(v[3], j)) };
        *(u16x4*)&tile[h * 64 + phys * 4] = o;
    }
    __syncthreads();
    const int h8 = threadIdx.x >> 3;   // 0..31
    const int dc = threadIdx.x & 7;    // 8-elem chunk of d
    #pragma unroll
    for (int p = 0; p < 2; ++p) {
        int h = p * 32 + h8;
        int p0 = (2 * dc)     ^ (h & 15);
        int p1 = (2 * dc + 1) ^ (h & 15);
        u16x8 o;
        o.lo = *(const u16x4*)&tile[h * 64 + p0 * 4];
        o.hi = *(const u16x4*)&tile[h * 64 + p1 * 4];
        *(u16x8*)(dst + (size_t)h * IN_DIM + dc * 8) = o;
    }
}

// ---------------- fused GEMM + bias + gelu + W2-dot (atomic partials) ----------------
__global__ __launch_bounds__(256, 3) void gemm_fused(
    const u16* __restrict__ xb,    // [4096][2048] bf16
    const u16* __restrict__ w1t,   // [40][1024][2048] bf16 (B^T: n-major, k-contig)
    const float* __restrict__ b1,  // [40][1024]
    const float* __restrict__ w2,  // [40][1024]
    float* __restrict__ partial)   // [4096][40], pre-zeroed
{
    __shared__ __align__(16) u16 smem[2 * BM * BK];   // A:[0,8192) B:[8192,16384) u16
    const int a  = blockIdx.z;
    const int m0 = blockIdx.x * BM;
    const int n0 = blockIdx.y * BN;

    const int tid  = threadIdx.x;
    const int w    = tid >> 6;
    const int l    = tid & 63;
    const int quad = l >> 4;
    const int lr   = l & 15;
    const int wm   = (w >> 1) * 64;
    const int wn   = (w & 1) * 64;

    // ---- loop-invariant staging offsets (elements) ----
    int offG[4];
    #pragma unroll
    for (int j = 0; j < 4; ++j) {
        int p   = j * 256 + tid;
        int row = p >> 3;
        int kc  = (p & 7) ^ (row & 7);
        offG[j] = row * IN_DIM + kc * 8;
    }
    // ---- loop-invariant LDS read offsets (u16 elements) ----
    int offLA[2][4], offLB[2][4];
    #pragma unroll
    for (int ks = 0; ks < 2; ++ks)
        #pragma unroll
        for (int f = 0; f < 4; ++f) {
            int rowA = wm + f * 16 + lr;
            int kcA  = (ks * 4 + quad) ^ (rowA & 7);
            offLA[ks][f] = rowA * BK + kcA * 8;
            int rowB = wn + f * 16 + lr;
            int kcB  = (ks * 4 + quad) ^ (rowB & 7);
            offLB[ks][f] = BM * BK + rowB * BK + kcB * 8;
        }

    const u16* Abase = xb + (size_t)m0 * IN_DIM;
    const u16* Bbase = w1t + (size_t)a * ((size_t)HID * IN_DIM) + (size_t)n0 * IN_DIM;

    f32x4 acc[4][4];
    #pragma unroll
    for (int i = 0; i < 4; ++i)
        #pragma unroll
        for (int j = 0; j < 4; ++j)
            acc[i][j] = (f32x4){0.f, 0.f, 0.f, 0.f};

    for (int k0 = 0; k0 < IN_DIM; k0 += BK) {
        const u16* Ak = Abase + k0;   // uniform: one scalar add/iter
        const u16* Bk = Bbase + k0;
        #pragma unroll
        for (int j = 0; j < 4; ++j)
            load16_to_lds(Ak + offG[j], &smem[(j * 256 + w * 64) * 8]);
        #pragma unroll
        for (int j = 0; j < 4; ++j)
            load16_to_lds(Bk + offG[j], &smem[BM * BK + (j * 256 + w * 64) * 8]);
        __syncthreads();

        #pragma unroll
        for (int ks = 0; ks < 2; ++ks) {
            bf16x8 af[4], bfr[4];
            #pragma unroll
            for (int f = 0; f < 4; ++f) af[f]  = *(const bf16x8*)&smem[offLA[ks][f]];
            #pragma unroll
            for (int f = 0; f < 4; ++f) bfr[f] = *(const bf16x8*)&smem[offLB[ks][f]];
            #pragma unroll
            for (int fm = 0; fm < 4; ++fm)
                #pragma unroll
                for (int fn = 0; fn < 4; ++fn)
                    acc[fm][fn] = __builtin_amdgcn_mfma_f32_16x16x32_bf16(
                        af[fm], bfr[fn], acc[fm][fn], 0, 0, 0);
        }
        __syncthreads();
    }

    // ---- epilogue: +b1, exact gelu, *W2, reduce over this tile's 128 cols ----
    float b1v[4], w2v[4];
    #pragma unroll
    for (int fn = 0; fn < 4; ++fn) {
        int col = n0 + wn + fn * 16 + lr;
        b1v[fn] = b1[a * HID + col];
        w2v[fn] = w2[a * HID + col];
    }
    #pragma unroll
    for (int fm = 0; fm < 4; ++fm) {
        #pragma unroll
        for (int r = 0; r < 4; ++r) {
            float s = 0.f;
            #pragma unroll
            for (int fn = 0; fn < 4; ++fn) {
                float z = acc[fm][fn][r] + b1v[fn];
                float g = 0.5f * z * (1.0f + erff(z * 0.70710678118654752f));
                s += g * w2v[fn];
            }
            s += __shfl_xor(s, 1, 64);
            s += __shfl_xor(s, 2, 64);
            s += __shfl_xor(s, 4, 64);
            s += __shfl_xor(s, 8, 64);
            if (lr == 0) {
                int grow = m0 + wm + fm * 16 + quad * 4 + r;
                atomicAdd(&partial[grow * ATT + a], s);
            }
        }
    }
}

// ---------------- sigmoid(partial + b2) -> out ----------------
__global__ void finish_kernel(const float* __restrict__ partial,
                              const float* __restrict__ b2,
                              float* __restrict__ out, int n) {
    int i = blockIdx.x * 256 + threadIdx.x;
    if (i < n) {
        float z = partial[i] + b2[i % ATT];
        out[i] = 1.0f / (1.0f + expf(-z));
    }
}

extern "C" void kernel_launch(void* const* d_in, const int* in_sizes, int n_in,
                              void* d_out, int out_size, void* d_ws, size_t ws_size,
                              hipStream_t stream) {
    const float* x  = (const float*)d_in[0];
    const float* W1 = (const float*)d_in[1];
    const float* b1 = (const float*)d_in[2];
    const float* W2 = (const float*)d_in[3];
    const float* b2 = (const float*)d_in[4];
    float* out = (float*)d_out;

    char* ws = (char*)d_ws;
    float* partial = (float*)ws;                                   // 640 KB
    u16*   xb      = (u16*)(ws + 655360);                          // 16 MB
    u16*   w1t     = (u16*)(ws + 655360 + 16777216);               // 160 MB

    hipMemsetAsync(partial, 0, (size_t)BATCH * ATT * sizeof(float), stream);
    convert_x<<<dim3(BATCH * IN_DIM / (256 * 4)), dim3(256), 0, stream>>>(x, xb);
    transpose_w1<<<dim3(HID / 64, IN_DIM / 64, ATT), dim3(256), 0, stream>>>(W1, w1t);
    gemm_fused<<<dim3(BATCH / BM, HID / BN, ATT), dim3(256), 0, stream>>>(
        xb, w1t, b1, W2, partial);
    finish_kernel<<<dim3((BATCH * ATT + 255) / 256), dim3(256), 0, stream>>>(
        partial, b2, out, BATCH * ATT);
}